// Round 10
// baseline (963.641 us; speedup 1.0000x reference)
//
#include <hip/hip_runtime.h>
#include <math.h>

// labels = argmin_k ||c1_k||^2 - 2*x.c1_k, x = inpt[:,64:128] (131072x64),
// centers1 (1024x64). centers0 unused. Output int32 labels.
constexpr int N_ROWS   = 131072;
constexpr int INPT_DIM = 128;
constexpr int DIM      = 64;
constexpr int COL_OFF  = 64;
constexpr int NCENT    = 1024;

constexpr int TM    = 128;          // rows per block (4 waves x 32 rows)
constexpr int NTILE = 64;           // tiles of 16 centers
constexpr int CHT   = 4;            // tiles per chunk (8 KB)
constexpr int NCH   = NTILE / CHT;  // 16 chunks
constexpr int MAXC  = 16;           // <=1 candidate per lane per row: can't overflow

typedef short short8 __attribute__((ext_vector_type(8)));
typedef float f32x4  __attribute__((ext_vector_type(4)));

// ws: [0,8192) f64 cnorm | [8192,12288) f32 cnorm | [12288,12292) maxC bits
//     [16384, 16384+131072) bf16 centers, MFMA-fragment-linear:
//     frag (tile t, khalf f) lane l: 8 bf16 at ((t*2+f)*64 + l)*16 bytes
//     = centers[t*16 + (l&15)][f*32 + (l>>4)*8 + j]   (B[n][k], m89 layout)

__device__ __forceinline__ unsigned f2bf(float f) {
    unsigned u = __float_as_uint(f);
    u += 0x7fff + ((u >> 16) & 1);          // round-to-nearest-even
    return u >> 16;
}

__device__ __forceinline__ double exact_score(const float* __restrict__ c,
                                              const float* __restrict__ x, double cn) {
    double acc = 0.0;
#pragma unroll
    for (int d = 0; d < DIM; ++d)
        acc = fma((double)c[d], (double)x[d], acc);
    return fma(-2.0, acc, cn);
}

// async global->LDS DMA, 16B per lane; LDS dest = wave-uniform base + lane*16
__device__ __forceinline__ void lds_dma16(const void* g, void* l) {
    __builtin_amdgcn_global_load_lds(
        (const __attribute__((address_space(1))) void*)g,
        (__attribute__((address_space(3))) void*)l, 16, 0, 0);
}

// ---------------------------------------------------------------------------
// Prep (unchanged from R6): 4 threads/center, coalesced 64B quarter-rows.
// ---------------------------------------------------------------------------
__global__ __launch_bounds__(256) void prep_kernel(const float* __restrict__ centers,
                                                   double* __restrict__ cnorm_d,
                                                   float* __restrict__ cnorm_f,
                                                   int* __restrict__ maxc_i,
                                                   unsigned short* __restrict__ cbf) {
    int tid = blockIdx.x * 256 + threadIdx.x;   // 0..4095
    int k = tid >> 2, kq = tid & 3;
    const float* c = centers + (size_t)k * DIM + kq * 16;
    float cf[16];
    double sd = 0.0;
#pragma unroll
    for (int j = 0; j < 4; ++j) {
        float4 v = *reinterpret_cast<const float4*>(c + j * 4);
        cf[j * 4] = v.x; cf[j * 4 + 1] = v.y; cf[j * 4 + 2] = v.z; cf[j * 4 + 3] = v.w;
        sd = fma((double)v.x, (double)v.x, sd);
        sd = fma((double)v.y, (double)v.y, sd);
        sd = fma((double)v.z, (double)v.z, sd);
        sd = fma((double)v.w, (double)v.w, sd);
    }
    sd += __shfl_xor(sd, 1);
    sd += __shfl_xor(sd, 2);
    if (kq == 0) { cnorm_d[k] = sd; cnorm_f[k] = (float)sd; }

    int t = k >> 4, n = k & 15, f = kq >> 1;
#pragma unroll
    for (int h = 0; h < 2; ++h) {
        int qq = (kq & 1) * 2 + h;
        const float* s = cf + h * 8;
        uint4 w;
        w.x = f2bf(s[0]) | (f2bf(s[1]) << 16);
        w.y = f2bf(s[2]) | (f2bf(s[3]) << 16);
        w.z = f2bf(s[4]) | (f2bf(s[5]) << 16);
        w.w = f2bf(s[6]) | (f2bf(s[7]) << 16);
        *reinterpret_cast<uint4*>(cbf + ((size_t)((t * 2 + f) * 64 + qq * 16 + n)) * 8) = w;
    }
    float nm = sqrtf((float)sd);
#pragma unroll
    for (int mk = 1; mk < 64; mk <<= 1)
        nm = fmaxf(nm, __shfl_xor(nm, mk));
    if ((threadIdx.x & 63) == 0) atomicMax(maxc_i, __float_as_int(nm));  // poison<0 loses
}

// ---------------------------------------------------------------------------
// Main: single pass, B staged via async global_load_lds double-buffer.
// Wave w owns rows [w*32, w*32+32) (2 A-frag sets); all waves read all tiles
// from shared LDS. Per (lane,row): min1/arg1/min2 over its 64 centers
// (center t*16+m lives only in lane-group m). Exactness: candidate centers
// (score < rowmin+margin) are each lane's min1 (collected) or witnessed by
// min2 < thresh -> row flagged uncertain (out=-1) -> fb_kernel exact-resolves.
// ---------------------------------------------------------------------------
__global__ __launch_bounds__(256) void label_kernel(
        const float* __restrict__ inpt, const float* __restrict__ centers,
        const double* __restrict__ cnorm_d, const float* __restrict__ cnorm_f,
        const int* __restrict__ maxc_i, const unsigned short* __restrict__ cbf,
        int* __restrict__ out) {
    __shared__ unsigned short A_lds[TM][72];   // 18.4 KB; frag reads 2-way (free)
    __shared__ float cn_lds[NCENT];            // 4 KB
    __shared__ float margin_lds[TM];
    __shared__ float nx2p[TM][2];
    __shared__ int   cand[TM][MAXC];           // 8 KB
    __shared__ int   ccount[TM];
    __shared__ int   urow[TM];
    __shared__ short8 bb[2][CHT * 2 * 64];     // 2 x 8 KB B double-buffer
    // total ~49.7 KB -> 3 blocks/CU -> 3 waves/EU -> ~170-VGPR regalloc budget

    const int tid  = threadIdx.x;
    const int lane = tid & 63;
    const int w    = tid >> 6;
    const int rowBase = blockIdx.x * TM;

    // ---- stage A (2 threads/row, 32 dims each) + cn + init
    {
        int r = tid >> 1, h = tid & 1;
        const float* xp = inpt + (size_t)(rowBase + r) * INPT_DIM + COL_OFF + h * 32;
        float ss = 0.f;
#pragma unroll
        for (int j = 0; j < 8; ++j) {
            float4 v = *reinterpret_cast<const float4*>(xp + j * 4);
            ss = fmaf(v.x, v.x, fmaf(v.y, v.y, fmaf(v.z, v.z, fmaf(v.w, v.w, ss))));
            unsigned u0 = f2bf(v.x) | (f2bf(v.y) << 16);
            unsigned u1 = f2bf(v.z) | (f2bf(v.w) << 16);
            *reinterpret_cast<unsigned*>(&A_lds[r][h * 32 + j * 4])     = u0;
            *reinterpret_cast<unsigned*>(&A_lds[r][h * 32 + j * 4 + 2]) = u1;
        }
        nx2p[r][h] = ss;
        *reinterpret_cast<float4*>(&cn_lds[tid * 4]) =
            *reinterpret_cast<const float4*>(cnorm_f + tid * 4);
        if (tid < TM) { ccount[tid] = 0; urow[tid] = 0; }
    }
    // issue DMA of chunk 0 (the syncthreads below drains it)
#pragma unroll
    for (int i = 0; i < 2; ++i) {
        const char* g = (const char*)cbf + w * 2048 + i * 1024 + lane * 16;
        char* l = (char*)&bb[0][0] + w * 2048 + i * 1024;   // wave-uniform base
        lds_dma16(g, l);
    }
    __syncthreads();

    if (tid < TM) {   // visible to all waves by the loop's first chunk-sync
        float nx2 = nx2p[tid][0] + nx2p[tid][1];
        // bf16 score err <= 2^-7|x||c| each way; formula unchanged since R3 (absmax=0)
        margin_lds[tid] = (1.5f / 64.f) * sqrtf(nx2) * __int_as_float(maxc_i[0]) + 1e-3f;
    }

    const int m = lane & 15, q = lane >> 4;
    short8 af0[2], af1[2];   // m89: A[m=lane&15][k=q*8+j]; sets w*2, w*2+1
#pragma unroll
    for (int s = 0; s < 2; ++s) {
        af0[s] = *reinterpret_cast<const short8*>(&A_lds[(w * 2 + s) * 16 + m][q * 8]);
        af1[s] = *reinterpret_cast<const short8*>(&A_lds[(w * 2 + s) * 16 + m][32 + q * 8]);
    }

    float min1[2][4], min2[2][4];
    int   arg1[2][4];
#pragma unroll
    for (int s = 0; s < 2; ++s)
#pragma unroll
        for (int r4 = 0; r4 < 4; ++r4) {
            min1[s][r4] = INFINITY; min2[s][r4] = INFINITY; arg1[s][r4] = 0;
        }

    // ---- chunk loop: DMA(c+1) -> compute(c) -> sync (drain lands after compute)
    for (int c = 0; c < NCH; ++c) {
        if (c + 1 < NCH) {
#pragma unroll
            for (int i = 0; i < 2; ++i) {
                const char* g = (const char*)cbf + (size_t)(c + 1) * 8192
                                + w * 2048 + i * 1024 + lane * 16;
                char* l = (char*)&bb[(c + 1) & 1][0] + w * 2048 + i * 1024;
                lds_dma16(g, l);
            }
        }
        const short8* B = &bb[c & 1][0];
#pragma unroll
        for (int i = 0; i < CHT; ++i) {
            int t = c * CHT + i;
            short8 b0 = B[i * 128 + lane];
            short8 b1 = B[i * 128 + 64 + lane];
            float cn = cn_lds[t * 16 + m];
#pragma unroll
            for (int s = 0; s < 2; ++s) {
                f32x4 acc = {0.f, 0.f, 0.f, 0.f};
                acc = __builtin_amdgcn_mfma_f32_16x16x32_bf16(af0[s], b0, acc, 0, 0, 0);
                acc = __builtin_amdgcn_mfma_f32_16x16x32_bf16(af1[s], b1, acc, 0, 0, 0);
#pragma unroll
                for (int r4 = 0; r4 < 4; ++r4) {   // D: col=m, row=q*4+r4
                    float sc = fmaf(-2.f, acc[r4], cn);
                    // min2 = median{min1,min2,sc}: one v_med3_f32
                    min2[s][r4] = __builtin_amdgcn_fmed3f(min1[s][r4], min2[s][r4], sc);
                    if (sc < min1[s][r4]) arg1[s][r4] = t;   // strict: first-min kept
                    min1[s][r4] = fminf(min1[s][r4], sc);
                }
            }
        }
        __syncthreads();
    }

    // ---- per-row reduce + candidate collect + uncertainty flag
#pragma unroll
    for (int s = 0; s < 2; ++s) {
#pragma unroll
        for (int r4 = 0; r4 < 4; ++r4) {
            int row = (w * 2 + s) * 16 + q * 4 + r4;
            float v = min1[s][r4];
            v = fminf(v, __shfl_xor(v, 1));
            v = fminf(v, __shfl_xor(v, 2));
            v = fminf(v, __shfl_xor(v, 4));
            v = fminf(v, __shfl_xor(v, 8));
            float th = v + margin_lds[row];
            unsigned long long bal = __ballot(min2[s][r4] < th);
            if (m == 0 && ((bal >> (q * 16)) & 0xFFFFull)) urow[row] = 1;
            if (min1[s][r4] < th) {          // <=1 per lane => <=16 per row
                int slot = atomicAdd(&ccount[row], 1);
                if (slot < MAXC) cand[row][slot] = arg1[s][r4] * 16 + m;
            }
        }
    }
    __syncthreads();

    // ---- resolve: certain rows exact-f64 over candidates; uncertain -> -1
    if (tid < TM) {
        int row = tid;
        if (urow[row]) {
            out[rowBase + row] = -1;         // fb_kernel rewrites exactly
        } else {
            int cnt = min(ccount[row], MAXC);
            int best;
            if (cnt == 1) {
                best = cand[row][0];
            } else {
                const float* xp = inpt + (size_t)(rowBase + row) * INPT_DIM + COL_OFF;
                double bestv = 1e300;
                best = 0x7fffffff;
                for (int j = 0; j < cnt; ++j) {
                    int k = cand[row][j];
                    double sE = exact_score(centers + (size_t)k * DIM, xp, cnorm_d[k]);
                    if (sE < bestv || (sE == bestv && k < best)) { bestv = sE; best = k; }
                }
            }
            out[rowBase + row] = best;
        }
    }
}

// ---------------------------------------------------------------------------
// Fallback: one wave per 64 rows scans out[] for -1; for each flagged row:
// f32 scores (registers) -> f64 rescore of everything within 4e-3 of the f32
// min (>= 10x the f32 dot error bound) -> f64 argmin, index tiebreak. Exact.
// ---------------------------------------------------------------------------
__global__ __launch_bounds__(256) void fb_kernel(
        const float* __restrict__ inpt, const float* __restrict__ centers,
        const double* __restrict__ cnorm_d, const float* __restrict__ cnorm_f,
        int* __restrict__ out) {
    int gwid = (blockIdx.x * 256 + threadIdx.x) >> 6;   // 0..2047
    int lane = threadIdx.x & 63;
    int base = gwid * 64;
    int v = out[base + lane];
    unsigned long long mask = __ballot(v < 0);
    while (mask) {
        int j = __ffsll(mask) - 1;
        mask &= mask - 1;
        int row = base + j;
        const float* xp = inpt + (size_t)row * INPT_DIM + COL_OFF;
        float x[DIM];                       // wave-uniform address -> scalarizable
#pragma unroll
        for (int d = 0; d < DIM; d += 4) {
            float4 t4 = *reinterpret_cast<const float4*>(xp + d);
            x[d] = t4.x; x[d + 1] = t4.y; x[d + 2] = t4.z; x[d + 3] = t4.w;
        }
        float s16[16];
        float lmin = INFINITY;
#pragma unroll
        for (int jj = 0; jj < 16; ++jj) {   // lane's centers: lane + 64*jj
            int k = lane + jj * 64;
            const float* c = centers + (size_t)k * DIM;
            float a = 0.f;
#pragma unroll
            for (int d = 0; d < DIM; ++d) a = fmaf(c[d], x[d], a);
            s16[jj] = fmaf(-2.f, a, cnorm_f[k]);
            lmin = fminf(lmin, s16[jj]);
        }
        float g = lmin;
#pragma unroll
        for (int sh = 1; sh < 64; sh <<= 1) g = fminf(g, __shfl_xor(g, sh));
        float th = g + 4e-3f;
        double bestv = 1e300;
        int bestk = 0x7fffffff;
#pragma unroll
        for (int jj = 0; jj < 16; ++jj) {
            if (s16[jj] < th) {
                int k = lane + jj * 64;
                double e = exact_score(centers + (size_t)k * DIM, x, cnorm_d[k]);
                if (e < bestv || (e == bestv && k < bestk)) { bestv = e; bestk = k; }
            }
        }
#pragma unroll
        for (int sh = 1; sh < 64; sh <<= 1) {
            double ov = __shfl_xor(bestv, sh);
            int    ok = __shfl_xor(bestk, sh);
            if (ov < bestv || (ov == bestv && ok < bestk)) { bestv = ov; bestk = ok; }
        }
        if (lane == 0) out[row] = bestk;
    }
}

// ---------------------------------------------------------------------------
extern "C" void kernel_launch(void* const* d_in, const int* in_sizes, int n_in,
                              void* d_out, int out_size, void* d_ws, size_t ws_size,
                              hipStream_t stream) {
    const float* inpt     = (const float*)d_in[0];
    const float* centers1 = (const float*)d_in[2];   // centers0 (d_in[1]) unused
    int* out = (int*)d_out;

    char* ws = (char*)d_ws;
    double* cnorm_d = (double*)ws;
    float*  cnorm_f = (float*)(ws + 8192);
    int*    maxc_i  = (int*)(ws + 12288);
    unsigned short* cbf = (unsigned short*)(ws + 16384);

    prep_kernel<<<16, 256, 0, stream>>>(centers1, cnorm_d, cnorm_f, maxc_i, cbf);
    label_kernel<<<N_ROWS / TM, 256, 0, stream>>>(inpt, centers1, cnorm_d, cnorm_f,
                                                  maxc_i, cbf, out);
    fb_kernel<<<512, 256, 0, stream>>>(inpt, centers1, cnorm_d, cnorm_f, out);
}